// Round 1
// baseline (214.232 us; speedup 1.0000x reference)
//
#include <hip/hip_runtime.h>

#define WD 7
#define NPAD 128
#define NCOLS 126
#define KDIM 8330
#define BSZ 4096
#define SPLITK 8
#define KSLICE 1042   // ceil(8330/8)
#define BM 64
#define BN 128
#define BK 32

static constexpr size_t WP_FLOATS   = (size_t)KDIM * NPAD;                     // 1,066,240
static constexpr size_t OFF_BIAS    = WP_FLOATS;                               // +128 floats
static constexpr size_t OFF_PART    = ((WP_FLOATS + NPAD + 255) / 256) * 256;  // 1,066,496
static constexpr size_t PART_FLOATS = (size_t)SPLITK * BSZ * NPAD;             // 4,194,304
static constexpr size_t OFF_VEC     = OFF_PART + PART_FLOATS;                  // 5,260,800
// total ws use: (OFF_VEC + BSZ*NPAD)*4 ≈ 23.1 MB

static __device__ const int KIDX[5][4] = {
    {0, 1, 3, 4}, {7, 8, 9, 10}, {5, 6, 11, 12}, {11, 12, 13, 14}, {15, 16, 15, 16}};
static __device__ const unsigned long long OBASE[5] = {0ull, 401408ull, 802816ull, 1204224ull, 1605632ull};

// ---------------- pack: W_{head,arm,upper,lower,foot} -> Wp[8330][128], bias -> bpacked[128]
__global__ __launch_bounds__(256) void pack_kernel(
    const float* __restrict__ Wh, const float* __restrict__ bh,
    const float* __restrict__ Wa, const float* __restrict__ ba,
    const float* __restrict__ Wu, const float* __restrict__ bu,
    const float* __restrict__ Wl, const float* __restrict__ bl,
    const float* __restrict__ Wf, const float* __restrict__ bf,
    float* __restrict__ ws) {
  int idx = blockIdx.x * 256 + threadIdx.x;
  const int total = KDIM * NPAD;
  if (idx < total) {
    int k = idx >> 7, n = idx & 127;
    float v = 0.f;
    if      (n < 28)  v = Wh[k * 28 + n];
    else if (n < 56)  v = Wa[k * 28 + (n - 28)];
    else if (n < 84)  v = Wu[k * 28 + (n - 56)];
    else if (n < 112) v = Wl[k * 28 + (n - 84)];
    else if (n < 126) v = Wf[k * 14 + (n - 112)];
    ws[idx] = v;
  } else if (idx < total + NPAD) {
    int n = idx - total;
    float v = 0.f;
    if      (n < 28)  v = bh[n];
    else if (n < 56)  v = ba[n - 28];
    else if (n < 84)  v = bu[n - 56];
    else if (n < 112) v = bl[n - 84];
    else if (n < 126) v = bf[n - 112];
    ws[OFF_BIAS + n] = v;
  }
}

// ---------------- GEMM: partial[s][4096][128] = x[:, ks:ke] @ Wp[ks:ke, :]
__global__ __launch_bounds__(256, 2) void gemm_kernel(const float* __restrict__ x,
                                                      float* __restrict__ ws) {
  const float* __restrict__ Wp = ws;
  float* __restrict__ partial = ws + OFF_PART;
  const int row0 = blockIdx.x * BM;
  const int split = blockIdx.y;
  const int ks = split * KSLICE;
  const int kend = min(ks + KSLICE, KDIM);

  __shared__ float xs[BM][BK + 1];
  __shared__ float wsh[BK][BN];

  const int tid = threadIdx.x;
  const int tx = tid & 15;   // 16 col groups of 8
  const int ty = tid >> 4;   // 16 row groups

  float acc[4][8];
#pragma unroll
  for (int i = 0; i < 4; ++i)
#pragma unroll
    for (int j = 0; j < 8; ++j) acc[i][j] = 0.f;

  for (int k0 = ks; k0 < kend; k0 += BK) {
    // stage x: 64 rows x 32 k as float2 (always 8B-aligned: 8330 even, k0 even)
#pragma unroll
    for (int j = 0; j < 4; ++j) {
      int idx = tid + 256 * j;
      int r = idx >> 4;            // 0..63
      int p = (idx & 15) << 1;     // 0..30 even
      int c = k0 + p;
      float f0 = 0.f, f1 = 0.f;
      if (c + 1 < kend) {
        float2 v = *reinterpret_cast<const float2*>(x + (size_t)(row0 + r) * KDIM + c);
        f0 = v.x; f1 = v.y;
      } else if (c < kend) {
        f0 = x[(size_t)(row0 + r) * KDIM + c];
      }
      xs[r][p] = f0;
      xs[r][p + 1] = f1;
    }
    // stage W: 32 k x 128 n as float4
#pragma unroll
    for (int j = 0; j < 4; ++j) {
      int idx = tid + 256 * j;
      int kk = idx >> 5;
      int n4 = (idx & 31) << 2;
      float4 v = make_float4(0.f, 0.f, 0.f, 0.f);
      if (k0 + kk < kend)
        v = *reinterpret_cast<const float4*>(Wp + (size_t)(k0 + kk) * NPAD + n4);
      *reinterpret_cast<float4*>(&wsh[kk][n4]) = v;
    }
    __syncthreads();
#pragma unroll 8
    for (int kk = 0; kk < BK; ++kk) {
      float xr[4];
#pragma unroll
      for (int i = 0; i < 4; ++i) xr[i] = xs[ty + 16 * i][kk];
      float4 w0 = *reinterpret_cast<const float4*>(&wsh[kk][tx * 8]);
      float4 w1 = *reinterpret_cast<const float4*>(&wsh[kk][tx * 8 + 4]);
#pragma unroll
      for (int i = 0; i < 4; ++i) {
        acc[i][0] += xr[i] * w0.x;
        acc[i][1] += xr[i] * w0.y;
        acc[i][2] += xr[i] * w0.z;
        acc[i][3] += xr[i] * w0.w;
        acc[i][4] += xr[i] * w1.x;
        acc[i][5] += xr[i] * w1.y;
        acc[i][6] += xr[i] * w1.z;
        acc[i][7] += xr[i] * w1.w;
      }
    }
    __syncthreads();
  }

#pragma unroll
  for (int i = 0; i < 4; ++i) {
    int r = row0 + ty + 16 * i;
    float* dst = partial + ((size_t)split * BSZ + r) * NPAD + tx * 8;
    *reinterpret_cast<float4*>(dst)     = make_float4(acc[i][0], acc[i][1], acc[i][2], acc[i][3]);
    *reinterpret_cast<float4*>(dst + 4) = make_float4(acc[i][4], acc[i][5], acc[i][6], acc[i][7]);
  }
}

// ---------------- reduce: vec = sum_s partial[s] + bias
__global__ __launch_bounds__(256) void reduce_kernel(float* __restrict__ ws) {
  int gid = blockIdx.x * 256 + threadIdx.x;
  const int total4 = BSZ * NPAD / 4;
  if (gid >= total4) return;
  const float4* part = reinterpret_cast<const float4*>(ws + OFF_PART);
  const float4* bias = reinterpret_cast<const float4*>(ws + OFF_BIAS);
  float4* vec = reinterpret_cast<float4*>(ws + OFF_VEC);
  int r = gid >> 5;
  int n4 = gid & 31;
  float4 s = part[(size_t)r * 32 + n4];
#pragma unroll
  for (int sp = 1; sp < SPLITK; ++sp) {
    float4 p = part[((size_t)sp * BSZ + r) * 32 + n4];
    s.x += p.x; s.y += p.y; s.z += p.z; s.w += p.w;
  }
  float4 bb = bias[n4];
  s.x += bb.x; s.y += bb.y; s.z += bb.z; s.w += bb.w;
  vec[gid] = s;
}

// ---------------- epilogue
__device__ __forceinline__ void axis_mask(const float a[WD], int lo, int hi, float m[WD]) {
  float am[WD];
  float tot = 0.f;
#pragma unroll
  for (int c = 0; c < WD; ++c) { am[c] = (c >= lo) ? a[c] : 0.f; tot += am[c]; }
  float run = 0.f;
  float c1[WD];
#pragma unroll
  for (int c = 0; c < WD; ++c) {
    run += am[c] / tot;
    c1[c] = (run >= 0.3f) ? run : 0.f;
  }
  float tot2 = 0.f;
#pragma unroll
  for (int c = 0; c < WD; ++c) { am[c] = (c < hi) ? a[c] : 0.f; tot2 += am[c]; }
  run = 0.f;
#pragma unroll
  for (int c = 0; c < WD; ++c) {
    run += am[c] / tot2;
    float c2 = 1.f - run;
    c2 = (c2 >= 0.3f) ? c2 : 0.f;
    m[c] = c1[c] * c2;
  }
}

__global__ __launch_bounds__(256) void epi_kernel(const float* __restrict__ ws,
                                                  const float* __restrict__ keypoint,
                                                  float* __restrict__ out) {
  int unit = blockIdx.x * 256 + threadIdx.x;
  if (unit >= BSZ * 5) return;
  int fam = unit >> 12;          // unit / 4096 : consecutive threads -> consecutive b
  int b = unit & (BSZ - 1);
  const float* vec = ws + OFF_VEC;

  const int G = (fam == 4) ? 1 : 2;
  const int nk = (fam == 4) ? 2 : 4;

  int mnx = 7, mxx = -1, mny = 7, mxy = -1;
  for (int i = 0; i < nk; ++i) {
    int kidx = KIDX[fam][i];
    float fx = keypoint[((size_t)b * 17 + kidx) * 2 + 0];
    float fy = keypoint[((size_t)b * 17 + kidx) * 2 + 1];
    int ix = (int)floorf(fx * 7.0f); ix = ix < 6 ? ix : 6;
    int iy = (int)floorf(fy * 7.0f); iy = iy < 6 ? iy : 6;
    mnx = min(mnx, ix); mxx = max(mxx, ix);
    mny = min(mny, iy); mxy = max(mxy, iy);
  }
  int lox = mnx - 1; if (lox < 0) lox = 0;
  int hix = mxx + 1; if (hix > 6) hix = 6;
  int loy = mny - 1; if (loy < 0) loy = 0;
  int hiy = mxy + 1; if (hiy > 6) hiy = 6;

  float xmg[2][WD], ymg[2][WD];
  float mx = 0.f;
#pragma unroll
  for (int g = 0; g < 2; ++g) {
    if (g < G) {
      const float* vg = vec + (size_t)b * NPAD + fam * 28 + g * 14;
      float a0[WD], a1[WD];
#pragma unroll
      for (int c = 0; c < WD; ++c) {
        float s0 = vg[c], s1 = vg[c + 7];
        float mM = fmaxf(s0, s1);
        float e0 = expf(s0 - mM), e1 = expf(s1 - mM);
        float sum = e0 + e1;
        a0[c] = expf(e0 / sum);
        a1[c] = expf(e1 / sum);
      }
      axis_mask(a0, lox, hix, xmg[g]);
      axis_mask(a1, loy, hiy, ymg[g]);
      float mx_x = 0.f, mx_y = 0.f;
#pragma unroll
      for (int c = 0; c < WD; ++c) {
        mx_x = fmaxf(mx_x, xmg[g][c]);
        mx_y = fmaxf(mx_y, ymg[g][c]);
      }
      mx = fmaxf(mx, mx_y * mx_x);
    }
  }

  float d = mx + 1e-7f;
  float* op = out + OBASE[fam] + (size_t)b * (G * 49);
#pragma unroll
  for (int g = 0; g < 2; ++g) {
    if (g < G) {
#pragma unroll
      for (int y = 0; y < WD; ++y) {
        float yv = ymg[g][y];
#pragma unroll
        for (int xx = 0; xx < WD; ++xx) {
          op[g * 49 + y * 7 + xx] = (yv * xmg[g][xx]) / d;
        }
      }
    }
  }
}

extern "C" void kernel_launch(void* const* d_in, const int* in_sizes, int n_in,
                              void* d_out, int out_size, void* d_ws, size_t ws_size,
                              hipStream_t stream) {
  const float* x        = (const float*)d_in[0];
  const float* keypoint = (const float*)d_in[1];
  const float* Wh = (const float*)d_in[2];
  const float* bh = (const float*)d_in[3];
  const float* Wa = (const float*)d_in[4];
  const float* ba = (const float*)d_in[5];
  const float* Wu = (const float*)d_in[6];
  const float* bu = (const float*)d_in[7];
  const float* Wl = (const float*)d_in[8];
  const float* bl = (const float*)d_in[9];
  const float* Wf = (const float*)d_in[10];
  const float* bf = (const float*)d_in[11];
  float* out = (float*)d_out;
  float* ws  = (float*)d_ws;

  const int packTotal = KDIM * NPAD + NPAD;
  hipLaunchKernelGGL(pack_kernel, dim3((packTotal + 255) / 256), dim3(256), 0, stream,
                     Wh, bh, Wa, ba, Wu, bu, Wl, bl, Wf, bf, ws);
  hipLaunchKernelGGL(gemm_kernel, dim3(BSZ / BM, SPLITK), dim3(256), 0, stream, x, ws);
  hipLaunchKernelGGL(reduce_kernel, dim3((BSZ * NPAD / 4) / 256), dim3(256), 0, stream, ws);
  hipLaunchKernelGGL(epi_kernel, dim3((BSZ * 5 + 255) / 256), dim3(256), 0, stream,
                     ws, keypoint, out);
}

// Round 2
// 112.370 us; speedup vs baseline: 1.9065x; 1.9065x over previous
//
#include <hip/hip_runtime.h>

typedef _Float16 half8 __attribute__((ext_vector_type(8)));
typedef float f32x4 __attribute__((ext_vector_type(4)));

#define WD 7
#define NPAD 128
#define KDIM 8330
#define KT 8384          // padded K for transposed W rows (131*64), 16B-aligned rows
#define BSZ 4096
#define SPLITK 8
#define KSLICE 1056      // multiple of BK; 7*1056=7392, split 7 handles 938 (+zero pad)
#define BM 64
#define BK 32

// ws layout (bytes)
static constexpr size_t OFF_WH   = 0;                          // _Float16[128][KT]
static constexpr size_t OFF_WL   = (size_t)NPAD * KT * 2;      // 2,146,304
static constexpr size_t OFF_BIAS = 2 * OFF_WL;                 // 4,292,608 (128 floats)
static constexpr size_t OFF_PART = OFF_BIAS + 512;             // 4,293,120 (16B aligned)
// partial: [SPLITK][BSZ][NPAD] f32 = 16,777,216 B. vec aliases partial[0].
// total: 21,070,336 B (< 23.1 MB proven available in round 1)

static __device__ const int KIDX[5][4] = {
    {0, 1, 3, 4}, {7, 8, 9, 10}, {5, 6, 11, 12}, {11, 12, 13, 14}, {15, 16, 15, 16}};
static __device__ const unsigned long long OBASE[5] = {0ull, 401408ull, 802816ull, 1204224ull, 1605632ull};

__device__ __forceinline__ unsigned pk16(_Float16 a, _Float16 b) {
  return (unsigned)__builtin_bit_cast(unsigned short, a) |
         ((unsigned)__builtin_bit_cast(unsigned short, b) << 16);
}

// ---------------- pack: W -> transposed fp16 hi/lo tiles Wt[n][k], bias
__global__ __launch_bounds__(256) void pack_kernel(
    const float* __restrict__ Wh, const float* __restrict__ bh,
    const float* __restrict__ Wa, const float* __restrict__ ba,
    const float* __restrict__ Wu, const float* __restrict__ bu,
    const float* __restrict__ Wl_, const float* __restrict__ bl,
    const float* __restrict__ Wf, const float* __restrict__ bf,
    char* __restrict__ wsb) {
  _Float16* wt_h = (_Float16*)(wsb + OFF_WH);
  _Float16* wt_l = (_Float16*)(wsb + OFF_WL);
  float* bias = (float*)(wsb + OFF_BIAS);
  __shared__ _Float16 sh[64][128];
  __shared__ _Float16 sl[64][128];
  const int k0 = blockIdx.x * 64;
  const int tid = threadIdx.x;

#pragma unroll
  for (int jj = 0; jj < 32; ++jj) {
    int idx = tid + 256 * jj;
    int kk = idx >> 7, n = idx & 127;
    int k = k0 + kk;
    float w = 0.f;
    if (k < KDIM) {
      if      (n < 28)  w = Wh [k * 28 + n];
      else if (n < 56)  w = Wa [k * 28 + (n - 28)];
      else if (n < 84)  w = Wu [k * 28 + (n - 56)];
      else if (n < 112) w = Wl_[k * 28 + (n - 84)];
      else if (n < 126) w = Wf [k * 14 + (n - 112)];
    }
    _Float16 h = (_Float16)w;
    _Float16 l = (_Float16)((w - (float)h) * 2048.0f);
    sh[kk][n] = h;
    sl[kk][n] = l;
  }
  if (blockIdx.x == 0 && tid < NPAD) {
    int n = tid;
    float v = 0.f;
    if      (n < 28)  v = bh[n];
    else if (n < 56)  v = ba[n - 28];
    else if (n < 84)  v = bu[n - 56];
    else if (n < 112) v = bl[n - 84];
    else if (n < 126) v = bf[n - 112];
    bias[n] = v;
  }
  __syncthreads();
  // transposed write: thread -> (n = tid>>1, kc = (tid&1)*32), 32 k's = 64B per buffer
  const int n = tid >> 1;
  const int kc = (tid & 1) * 32;
  size_t ob = (size_t)n * KT + k0 + kc;
#pragma unroll
  for (int c = 0; c < 4; ++c) {
    uint4 qh, ql;
    qh.x = pk16(sh[kc + c * 8 + 0][n], sh[kc + c * 8 + 1][n]);
    qh.y = pk16(sh[kc + c * 8 + 2][n], sh[kc + c * 8 + 3][n]);
    qh.z = pk16(sh[kc + c * 8 + 4][n], sh[kc + c * 8 + 5][n]);
    qh.w = pk16(sh[kc + c * 8 + 6][n], sh[kc + c * 8 + 7][n]);
    ql.x = pk16(sl[kc + c * 8 + 0][n], sl[kc + c * 8 + 1][n]);
    ql.y = pk16(sl[kc + c * 8 + 2][n], sl[kc + c * 8 + 3][n]);
    ql.z = pk16(sl[kc + c * 8 + 4][n], sl[kc + c * 8 + 5][n]);
    ql.w = pk16(sl[kc + c * 8 + 6][n], sl[kc + c * 8 + 7][n]);
    *(uint4*)(wt_h + ob + c * 8) = qh;
    *(uint4*)(wt_l + ob + c * 8) = ql;
  }
}

// ---------------- GEMM: partial[s] = x[:, slice] @ W[slice, :]  (fp16x3 via MFMA)
__global__ __launch_bounds__(256, 2) void gemm_kernel(const float* __restrict__ x,
                                                      char* __restrict__ wsb) {
  const _Float16* wt_h = (const _Float16*)(wsb + OFF_WH);
  const _Float16* wt_l = (const _Float16*)(wsb + OFF_WL);
  float* partial = (float*)(wsb + OFF_PART);
  const int row0 = blockIdx.x * BM;
  const int split = blockIdx.y;
  const int ks = split * KSLICE;
  const int kend = min(ks + KSLICE, KDIM);

  __shared__ _Float16 xs_h[BM][BK];     // 4KB
  __shared__ _Float16 xs_l[BM][BK];     // 4KB
  __shared__ _Float16 wh_s[NPAD][BK];   // 8KB  (n-major, k contiguous)
  __shared__ _Float16 wl_s[NPAD][BK];   // 8KB

  const int tid = threadIdx.x;
  const int lane = tid & 63;
  const int wid = tid >> 6;       // 0..3
  const int wm = wid & 1;         // row half (32 rows)
  const int wn = wid >> 1;        // col half (64 cols)
  const int lr = lane & 15;
  const int lk = (lane >> 4) * 8;

  f32x4 accA[2][4], accB[2][4];
#pragma unroll
  for (int m = 0; m < 2; ++m)
#pragma unroll
    for (int n = 0; n < 4; ++n) {
      accA[m][n] = (f32x4)(0.f);
      accB[m][n] = (f32x4)(0.f);
    }

  const int xrow = tid >> 2;          // 0..63
  const int xkc = (tid & 3) * 8;      // 0,8,16,24
  const float* xrp = x + (size_t)(row0 + xrow) * KDIM;

  for (int k0 = ks; k0 < kend; k0 += BK) {
    // ---- stage x (fp32 -> hi/lo fp16)
    float xv[8];
#pragma unroll
    for (int j = 0; j < 4; ++j) {
      int c = k0 + xkc + 2 * j;
      float2 v = make_float2(0.f, 0.f);
      if (c + 1 < kend) v = *(const float2*)(xrp + c);
      else if (c < kend) v.x = xrp[c];
      xv[2 * j] = v.x;
      xv[2 * j + 1] = v.y;
    }
    uint4 qh, ql;
    {
      _Float16 h0 = (_Float16)xv[0], h1 = (_Float16)xv[1], h2 = (_Float16)xv[2], h3 = (_Float16)xv[3];
      _Float16 h4 = (_Float16)xv[4], h5 = (_Float16)xv[5], h6 = (_Float16)xv[6], h7 = (_Float16)xv[7];
      qh.x = pk16(h0, h1); qh.y = pk16(h2, h3); qh.z = pk16(h4, h5); qh.w = pk16(h6, h7);
      ql.x = pk16((_Float16)((xv[0] - (float)h0) * 2048.0f), (_Float16)((xv[1] - (float)h1) * 2048.0f));
      ql.y = pk16((_Float16)((xv[2] - (float)h2) * 2048.0f), (_Float16)((xv[3] - (float)h3) * 2048.0f));
      ql.z = pk16((_Float16)((xv[4] - (float)h4) * 2048.0f), (_Float16)((xv[5] - (float)h5) * 2048.0f));
      ql.w = pk16((_Float16)((xv[6] - (float)h6) * 2048.0f), (_Float16)((xv[7] - (float)h7) * 2048.0f));
    }
    *(uint4*)&xs_h[xrow][xkc] = qh;
    *(uint4*)&xs_l[xrow][xkc] = ql;
    // ---- stage W (pre-converted fp16, k-contiguous rows; tail reads hit zeroed pad)
#pragma unroll
    for (int j = 0; j < 2; ++j) {
      int idx = tid + 256 * j;
      int n = idx >> 2, kg = (idx & 3) * 8;
      *(uint4*)&wh_s[n][kg] = *(const uint4*)(wt_h + (size_t)n * KT + k0 + kg);
      *(uint4*)&wl_s[n][kg] = *(const uint4*)(wt_l + (size_t)n * KT + k0 + kg);
    }
    __syncthreads();

    half8 ah[2], al[2], bhf[4], blf[4];
#pragma unroll
    for (int m = 0; m < 2; ++m) {
      ah[m] = *(const half8*)&xs_h[wm * 32 + m * 16 + lr][lk];
      al[m] = *(const half8*)&xs_l[wm * 32 + m * 16 + lr][lk];
    }
#pragma unroll
    for (int n = 0; n < 4; ++n) {
      bhf[n] = *(const half8*)&wh_s[wn * 64 + n * 16 + lr][lk];
      blf[n] = *(const half8*)&wl_s[wn * 64 + n * 16 + lr][lk];
    }
#pragma unroll
    for (int m = 0; m < 2; ++m)
#pragma unroll
      for (int n = 0; n < 4; ++n) {
        accA[m][n] = __builtin_amdgcn_mfma_f32_16x16x32_f16(ah[m], bhf[n], accA[m][n], 0, 0, 0);
        accB[m][n] = __builtin_amdgcn_mfma_f32_16x16x32_f16(al[m], bhf[n], accB[m][n], 0, 0, 0);
        accB[m][n] = __builtin_amdgcn_mfma_f32_16x16x32_f16(ah[m], blf[n], accB[m][n], 0, 0, 0);
      }
    __syncthreads();
  }

  float* pb = partial + (size_t)split * BSZ * NPAD;
#pragma unroll
  for (int m = 0; m < 2; ++m)
#pragma unroll
    for (int n = 0; n < 4; ++n)
#pragma unroll
      for (int r = 0; r < 4; ++r) {
        int row = row0 + wm * 32 + m * 16 + (lane >> 4) * 4 + r;
        int col = wn * 64 + n * 16 + lr;
        pb[(size_t)row * NPAD + col] = accA[m][n][r] + accB[m][n][r] * (1.0f / 2048.0f);
      }
}

// ---------------- reduce: vec (= partial[0], in place) = sum_s partial[s] + bias
__global__ __launch_bounds__(256) void reduce_kernel(char* __restrict__ wsb) {
  int gid = blockIdx.x * 256 + threadIdx.x;
  const int total4 = BSZ * NPAD / 4;
  if (gid >= total4) return;
  float4* part = (float4*)(wsb + OFF_PART);
  const float4* bias = (const float4*)(wsb + OFF_BIAS);
  float4 s = part[gid];
#pragma unroll
  for (int sp = 1; sp < SPLITK; ++sp) {
    float4 p = part[(size_t)sp * (BSZ * NPAD / 4) + gid];
    s.x += p.x; s.y += p.y; s.z += p.z; s.w += p.w;
  }
  float4 bb = bias[gid & 31];
  s.x += bb.x; s.y += bb.y; s.z += bb.z; s.w += bb.w;
  part[gid] = s;
}

// ---------------- epilogue (unchanged from passing round-1 version)
__device__ __forceinline__ void axis_mask(const float a[WD], int lo, int hi, float m[WD]) {
  float am[WD];
  float tot = 0.f;
#pragma unroll
  for (int c = 0; c < WD; ++c) { am[c] = (c >= lo) ? a[c] : 0.f; tot += am[c]; }
  float run = 0.f;
  float c1[WD];
#pragma unroll
  for (int c = 0; c < WD; ++c) {
    run += am[c] / tot;
    c1[c] = (run >= 0.3f) ? run : 0.f;
  }
  float tot2 = 0.f;
#pragma unroll
  for (int c = 0; c < WD; ++c) { am[c] = (c < hi) ? a[c] : 0.f; tot2 += am[c]; }
  run = 0.f;
#pragma unroll
  for (int c = 0; c < WD; ++c) {
    run += am[c] / tot2;
    float c2 = 1.f - run;
    c2 = (c2 >= 0.3f) ? c2 : 0.f;
    m[c] = c1[c] * c2;
  }
}

__global__ __launch_bounds__(256) void epi_kernel(const char* __restrict__ wsb,
                                                  const float* __restrict__ keypoint,
                                                  float* __restrict__ out) {
  int unit = blockIdx.x * 256 + threadIdx.x;
  if (unit >= BSZ * 5) return;
  int fam = unit >> 12;
  int b = unit & (BSZ - 1);
  const float* vec = (const float*)(wsb + OFF_PART);

  const int G = (fam == 4) ? 1 : 2;
  const int nk = (fam == 4) ? 2 : 4;

  int mnx = 7, mxx = -1, mny = 7, mxy = -1;
  for (int i = 0; i < nk; ++i) {
    int kidx = KIDX[fam][i];
    float fx = keypoint[((size_t)b * 17 + kidx) * 2 + 0];
    float fy = keypoint[((size_t)b * 17 + kidx) * 2 + 1];
    int ix = (int)floorf(fx * 7.0f); ix = ix < 6 ? ix : 6;
    int iy = (int)floorf(fy * 7.0f); iy = iy < 6 ? iy : 6;
    mnx = min(mnx, ix); mxx = max(mxx, ix);
    mny = min(mny, iy); mxy = max(mxy, iy);
  }
  int lox = mnx - 1; if (lox < 0) lox = 0;
  int hix = mxx + 1; if (hix > 6) hix = 6;
  int loy = mny - 1; if (loy < 0) loy = 0;
  int hiy = mxy + 1; if (hiy > 6) hiy = 6;

  float xmg[2][WD], ymg[2][WD];
  float mx = 0.f;
#pragma unroll
  for (int g = 0; g < 2; ++g) {
    if (g < G) {
      const float* vg = vec + (size_t)b * NPAD + fam * 28 + g * 14;
      float a0[WD], a1[WD];
#pragma unroll
      for (int c = 0; c < WD; ++c) {
        float s0 = vg[c], s1 = vg[c + 7];
        float mM = fmaxf(s0, s1);
        float e0 = expf(s0 - mM), e1 = expf(s1 - mM);
        float sum = e0 + e1;
        a0[c] = expf(e0 / sum);
        a1[c] = expf(e1 / sum);
      }
      axis_mask(a0, lox, hix, xmg[g]);
      axis_mask(a1, loy, hiy, ymg[g]);
      float mx_x = 0.f, mx_y = 0.f;
#pragma unroll
      for (int c = 0; c < WD; ++c) {
        mx_x = fmaxf(mx_x, xmg[g][c]);
        mx_y = fmaxf(mx_y, ymg[g][c]);
      }
      mx = fmaxf(mx, mx_y * mx_x);
    }
  }

  float d = mx + 1e-7f;
  float* op = out + OBASE[fam] + (size_t)b * (G * 49);
#pragma unroll
  for (int g = 0; g < 2; ++g) {
    if (g < G) {
#pragma unroll
      for (int y = 0; y < WD; ++y) {
        float yv = ymg[g][y];
#pragma unroll
        for (int xx = 0; xx < WD; ++xx) {
          op[g * 49 + y * 7 + xx] = (yv * xmg[g][xx]) / d;
        }
      }
    }
  }
}

extern "C" void kernel_launch(void* const* d_in, const int* in_sizes, int n_in,
                              void* d_out, int out_size, void* d_ws, size_t ws_size,
                              hipStream_t stream) {
  const float* x        = (const float*)d_in[0];
  const float* keypoint = (const float*)d_in[1];
  const float* Wh = (const float*)d_in[2];
  const float* bh = (const float*)d_in[3];
  const float* Wa = (const float*)d_in[4];
  const float* ba = (const float*)d_in[5];
  const float* Wu = (const float*)d_in[6];
  const float* bu = (const float*)d_in[7];
  const float* Wl = (const float*)d_in[8];
  const float* bl = (const float*)d_in[9];
  const float* Wf = (const float*)d_in[10];
  const float* bf = (const float*)d_in[11];
  float* out = (float*)d_out;
  char* wsb  = (char*)d_ws;

  hipLaunchKernelGGL(pack_kernel, dim3(KT / 64), dim3(256), 0, stream,
                     Wh, bh, Wa, ba, Wu, bu, Wl, bl, Wf, bf, wsb);
  hipLaunchKernelGGL(gemm_kernel, dim3(BSZ / BM, SPLITK), dim3(256), 0, stream, x, wsb);
  hipLaunchKernelGGL(reduce_kernel, dim3(BSZ * NPAD / 4 / 256), dim3(256), 0, stream, wsb);
  hipLaunchKernelGGL(epi_kernel, dim3(BSZ * 5 / 256), dim3(256), 0, stream,
                     wsb, keypoint, out);
}